// Round 3
// baseline (398.767 us; speedup 1.0000x reference)
//
#include <hip/hip_runtime.h>

// Problem: fasterRCNN box decode + per-class argmax region pick.
// Inputs (float32): boxes (N,4), box_deltas (N,28), scores (N,7), im_info (3)
// Outputs (float32, concatenated): pred_boxes (N*28), region_g (5), region_l (5)
//
// SINGLE fused kernel (round-2 post-mortem: bench dur ~250 us vs decode
// dispatch ~85 us -> the single-block finalize kernel + 2nd launch were
// ~2/3 of the timed region; decode was never the main bill).
//
// Stage 1 (per-block): one thread per (row,class) pair p = i*7+c, simple
//   grid-stride (round-0 structure: fastest measured, 79.9 us; x4 unrolls
//   regressed twice). deltas/pred float4 coalesced; scores flat; boxes
//   broadcast via L1. Per-class argmax (classes 1..6), exact first-index
//   tie-break: key = (monotone(score)<<32) | (0xFFFFFFFF - i); LDS
//   atomicMax with 4B hi-word pre-check; sbest init to THRESH key.
// Stage 2 (fused): per-block winners -> 6-entry GLOBAL atomicMax (device
//   scope, ~12K atomics total). Last-block-done pattern: __threadfence()
//   release + atomic counter; last block's tid0 reads the 6 winners
//   coherently (atomicMax(p,0)), picks the 2 region winners, gathers the
//   4-float box from pred (acquire fence first), writes 2x5 floats.
//   Counter+gmax zeroed by a 64 B hipMemsetAsync each launch (graph-legal).

#define THRESH_F 0.05f
#define NCLS 7
#define BLOCKS 2048
#define TPB 256

typedef float f4 __attribute__((ext_vector_type(4)));

__device__ __forceinline__ unsigned map_float(unsigned bits) {
    // monotone map float bits -> unsigned (order-preserving for all finite floats)
    return (bits & 0x80000000u) ? ~bits : (bits | 0x80000000u);
}

__global__ __launch_bounds__(TPB) void decode_pick_kernel(
    const f4*   __restrict__ boxes,
    const f4*   __restrict__ deltas,
    const float* __restrict__ scores,
    const float* __restrict__ im_info,
    f4*         __restrict__ pred,
    unsigned*            __restrict__ counter,   // d_ws + 0
    unsigned long long*  __restrict__ gmax,      // d_ws + 8, 6 slots
    float*               __restrict__ regions,   // d_out + N*28, 10 floats
    int NP)
{
    __shared__ unsigned long long sbest[6];
    __shared__ int is_last;
    const int tid = threadIdx.x;
    if (tid < 6)
        sbest[tid] = ((unsigned long long)map_float(__float_as_uint(THRESH_F)) << 32);
    __syncthreads();

    const float maxX = im_info[1] - 1.0f;   // W-1 = 999
    const float maxY = im_info[0] - 1.0f;   // H-1 = 599

    const int stride = gridDim.x * blockDim.x;
    for (int p = blockIdx.x * blockDim.x + tid; p < NP; p += stride) {
        const unsigned up = (unsigned)p;
        const unsigned i  = up / 7u;          // compiler magic-mul
        const unsigned c  = up - i * 7u;

        const f4 d = deltas[p];
        const f4 b = boxes[i];

        const float w  = b.z - b.x + 1.0f;
        const float h  = b.w - b.y + 1.0f;
        const float cx = b.x + 0.5f * w;
        const float cy = b.y + 0.5f * h;

        const float pcx = (d.x * 0.1f) * w + cx;
        const float pcy = (d.y * 0.1f) * h + cy;
        const float pw  = __expf(d.z * 0.2f) * w * 0.5f;
        const float ph  = __expf(d.w * 0.2f) * h * 0.5f;

        f4 o;
        o.x = fminf(fmaxf(pcx - pw, 0.0f), maxX);
        o.y = fminf(fmaxf(pcy - ph, 0.0f), maxY);
        o.z = fminf(fmaxf(pcx + pw, 0.0f), maxX);
        o.w = fminf(fmaxf(pcy + ph, 0.0f), maxY);
        pred[p] = o;

        if (c != 0u) {
            const float s = scores[p];
            const float m = (s > THRESH_F) ? s : -1.0f;
            const unsigned mapped = map_float(__float_as_uint(m));
            const int slot = (int)c - 1;
            // 4B hi-word pre-check (atomic wrt tearing) to skip most LDS atomics
            const unsigned curhi = ((volatile const unsigned*)sbest)[slot * 2 + 1];
            if (mapped >= curhi) {
                const unsigned long long key =
                    ((unsigned long long)mapped << 32) |
                    (unsigned long long)(0xFFFFFFFFu - i);
                atomicMax(&sbest[slot], key);
            }
        }
    }
    __syncthreads();

    // ---- publish block winners to device-scope global max ----
    if (tid < 6)
        atomicMax(&gmax[tid], sbest[tid]);
    __syncthreads();
    __threadfence();                 // release: pred stores + atomics visible
    if (tid == 0) {
        const unsigned old = atomicAdd(counter, 1u);
        is_last = (old == gridDim.x - 1u) ? 1 : 0;
    }
    __syncthreads();

    // ---- last block: tiny finalize (2 regions) ----
    if (is_last && tid == 0) {
        __threadfence();             // acquire: see all blocks' pred stores
        for (int g = 0; g < 2; ++g) {
            float sc_[3];
            unsigned idx_[3];
            float bestScore = -1e30f;
            int bestJ = 0;
            for (int j = 0; j < 3; ++j) {
                // coherent read of the global winner
                const unsigned long long key = atomicMax(&gmax[g * 3 + j], 0ULL);
                const unsigned hi = (unsigned)(key >> 32);
                const unsigned bits = (hi & 0x80000000u) ? (hi & 0x7FFFFFFFu) : ~hi;
                sc_[j] = __uint_as_float(bits);
                idx_[j] = 0xFFFFFFFFu - (unsigned)(key & 0xFFFFFFFFu);
                if (sc_[j] > bestScore) { bestScore = sc_[j]; bestJ = j; }  // strict > : first-max
            }
            const int c = g * 3 + bestJ + 1;
            const unsigned i = idx_[bestJ];
            const float* pb = (const float*)pred + (size_t)i * 28 + (size_t)c * 4;
            float* r = regions + g * 5;
            r[0] = pb[0];
            r[1] = pb[1];
            r[2] = pb[2];
            r[3] = pb[3];
            r[4] = sc_[bestJ];
        }
    }
}

extern "C" void kernel_launch(void* const* d_in, const int* in_sizes, int n_in,
                              void* d_out, int out_size, void* d_ws, size_t ws_size,
                              hipStream_t stream) {
    const float* boxes   = (const float*)d_in[0];
    const float* deltas  = (const float*)d_in[1];
    const float* scores  = (const float*)d_in[2];
    const float* im_info = (const float*)d_in[3];

    const int N  = in_sizes[0] / 4;      // 1,000,000
    const int NP = N * NCLS;             // 7,000,000 (row,class) pairs

    float* out = (float*)d_out;
    float* regions = out + (size_t)N * 4 * NCLS;   // after pred_boxes

    // d_ws: [0..3] counter, [8..55] 6x u64 global max keys
    hipMemsetAsync(d_ws, 0, 64, stream);

    unsigned* counter = (unsigned*)d_ws;
    unsigned long long* gmax = (unsigned long long*)((char*)d_ws + 8);

    decode_pick_kernel<<<BLOCKS, TPB, 0, stream>>>(
        (const f4*)boxes, (const f4*)deltas, scores, im_info,
        (f4*)out, counter, gmax, regions, NP);
}

// Round 4
// 236.217 us; speedup vs baseline: 1.6881x; 1.6881x over previous
//
#include <hip/hip_runtime.h>

// Problem: fasterRCNN box decode + per-class argmax region pick.
// Inputs (float32): boxes (N,4), box_deltas (N,28), scores (N,7), im_info (3)
// Outputs (float32, concatenated): pred_boxes (N*28), region_g (5), region_l (5)
//
// Round-3 post-mortem: single-kernel fusion REGRESSED 3x (all 2048 blocks
// co-resident -> ~14K same-line device-scope atomics stampede across 8
// non-coherent XCD L2s; VALUBusy 12%->4%). Also resolved accounting: the
// fixed ~142 us gap between total and kernel time is HARNESS-side
// (reset/re-poison dispatches); the old finalize+launch was only ~23 us.
// Decode at ~80 us is invariant to access restructuring and to read source
// (HBM vs L3) -> pinned by the shared L3/write-path funnel at ~3.3 TB/s
// for its required 268 MB; keep the round-0 structure (best measured).
//
// Stage 1: one thread per (row,class) pair p = i*7+c, simple grid-stride.
//   deltas/pred float4 coalesced; scores flat; boxes L1-broadcast.
//   Per-class argmax (classes 1..6), exact first-index tie-break:
//   key = (monotone(score)<<32) | (0xFFFFFFFF - i); LDS atomicMax with
//   4B hi-word pre-check; sbest init to THRESH key (no iter-0 stampede).
//   Winners stored SLOT-MAJOR: blockbest[slot*gridDim + block] so finalize
//   reads are coalesced.
// Stage 2 (tiny, 1 block x 384 threads): wave w (of 6) owns slot w, reads
//   its 2048 winners fully coalesced (64 lanes x 8B), reduces in-wave via
//   __shfl_xor butterfly (no barrier tree), one __syncthreads, tid0 does
//   the 2-region epilogue.

#define THRESH_F 0.05f
#define NCLS 7
#define BLOCKS 2048
#define TPB 256
#define FIN_TPB 384   // 6 waves, one per slot

typedef float f4 __attribute__((ext_vector_type(4)));

__device__ __forceinline__ unsigned map_float(unsigned bits) {
    // monotone map float bits -> unsigned (order-preserving for all finite floats)
    return (bits & 0x80000000u) ? ~bits : (bits | 0x80000000u);
}

__global__ __launch_bounds__(TPB) void decode_pick_kernel(
    const f4*   __restrict__ boxes,
    const f4*   __restrict__ deltas,
    const float* __restrict__ scores,
    const float* __restrict__ im_info,
    f4*         __restrict__ pred,
    unsigned long long* __restrict__ blockbest,   // slot-major [6][BLOCKS]
    int NP)
{
    __shared__ unsigned long long sbest[6];
    const int tid = threadIdx.x;
    if (tid < 6)
        sbest[tid] = ((unsigned long long)map_float(__float_as_uint(THRESH_F)) << 32);
    __syncthreads();

    const float maxX = im_info[1] - 1.0f;   // W-1 = 999
    const float maxY = im_info[0] - 1.0f;   // H-1 = 599

    const int stride = gridDim.x * blockDim.x;
    for (int p = blockIdx.x * blockDim.x + tid; p < NP; p += stride) {
        const unsigned up = (unsigned)p;
        const unsigned i  = up / 7u;          // compiler magic-mul
        const unsigned c  = up - i * 7u;

        const f4 d = deltas[p];
        const f4 b = boxes[i];

        const float w  = b.z - b.x + 1.0f;
        const float h  = b.w - b.y + 1.0f;
        const float cx = b.x + 0.5f * w;
        const float cy = b.y + 0.5f * h;

        const float pcx = (d.x * 0.1f) * w + cx;
        const float pcy = (d.y * 0.1f) * h + cy;
        const float pw  = __expf(d.z * 0.2f) * w * 0.5f;
        const float ph  = __expf(d.w * 0.2f) * h * 0.5f;

        f4 o;
        o.x = fminf(fmaxf(pcx - pw, 0.0f), maxX);
        o.y = fminf(fmaxf(pcy - ph, 0.0f), maxY);
        o.z = fminf(fmaxf(pcx + pw, 0.0f), maxX);
        o.w = fminf(fmaxf(pcy + ph, 0.0f), maxY);
        pred[p] = o;

        if (c != 0u) {
            const float s = scores[p];
            const float m = (s > THRESH_F) ? s : -1.0f;
            const unsigned mapped = map_float(__float_as_uint(m));
            const int slot = (int)c - 1;
            // 4B hi-word pre-check (atomic wrt tearing) to skip most LDS atomics
            const unsigned curhi = ((volatile const unsigned*)sbest)[slot * 2 + 1];
            if (mapped >= curhi) {
                const unsigned long long key =
                    ((unsigned long long)mapped << 32) |
                    (unsigned long long)(0xFFFFFFFFu - i);
                atomicMax(&sbest[slot], key);
            }
        }
    }
    __syncthreads();
    if (tid < 6)
        blockbest[(size_t)tid * gridDim.x + blockIdx.x] = sbest[tid];
}

__global__ __launch_bounds__(FIN_TPB) void finalize_kernel(
    const unsigned long long* __restrict__ blockbest,  // slot-major [6][nblocks]
    int nblocks,
    const float* __restrict__ pred,
    float*       __restrict__ regions)   // d_out + N*28, 10 floats
{
    __shared__ unsigned long long fin[6];
    const int tid  = threadIdx.x;
    const int wave = tid >> 6;        // 0..5 -> slot
    const int lane = tid & 63;

    // each wave reduces its slot's nblocks winners, fully coalesced
    unsigned long long k = 0ULL;
    const unsigned long long* src = blockbest + (size_t)wave * nblocks;
    for (int j = lane; j < nblocks; j += 64) {
        const unsigned long long v = src[j];
        k = (v > k) ? v : k;
    }
    // in-wave butterfly max (64 lanes)
    for (int off = 32; off > 0; off >>= 1) {
        const unsigned long long v = __shfl_xor(k, off, 64);
        k = (v > k) ? v : k;
    }
    if (lane == 0) fin[wave] = k;
    __syncthreads();

    if (tid == 0) {
        for (int g = 0; g < 2; ++g) {
            float sc_[3];
            unsigned idx_[3];
            float bestScore = -1e30f;
            int bestJ = 0;
            for (int j = 0; j < 3; ++j) {
                const unsigned long long key = fin[g * 3 + j];
                const unsigned hi = (unsigned)(key >> 32);
                const unsigned bits = (hi & 0x80000000u) ? (hi & 0x7FFFFFFFu) : ~hi;
                sc_[j] = __uint_as_float(bits);
                idx_[j] = 0xFFFFFFFFu - (unsigned)(key & 0xFFFFFFFFu);
                if (sc_[j] > bestScore) { bestScore = sc_[j]; bestJ = j; }  // strict > : first-max
            }
            const int c = g * 3 + bestJ + 1;
            const unsigned i = idx_[bestJ];
            const float* pb = pred + (size_t)i * 28 + (size_t)c * 4;
            float* r = regions + g * 5;
            r[0] = pb[0];
            r[1] = pb[1];
            r[2] = pb[2];
            r[3] = pb[3];
            r[4] = sc_[bestJ];
        }
    }
}

extern "C" void kernel_launch(void* const* d_in, const int* in_sizes, int n_in,
                              void* d_out, int out_size, void* d_ws, size_t ws_size,
                              hipStream_t stream) {
    const float* boxes   = (const float*)d_in[0];
    const float* deltas  = (const float*)d_in[1];
    const float* scores  = (const float*)d_in[2];
    const float* im_info = (const float*)d_in[3];

    const int N  = in_sizes[0] / 4;      // 1,000,000
    const int NP = N * NCLS;             // 7,000,000 (row,class) pairs

    float* out = (float*)d_out;
    float* regions = out + (size_t)N * 4 * NCLS;   // after pred_boxes

    unsigned long long* blockbest = (unsigned long long*)d_ws;  // 6*BLOCKS*8 = 96 KB

    decode_pick_kernel<<<BLOCKS, TPB, 0, stream>>>(
        (const f4*)boxes, (const f4*)deltas, scores, im_info,
        (f4*)out, blockbest, NP);

    finalize_kernel<<<1, FIN_TPB, 0, stream>>>(blockbest, BLOCKS, out, regions);
}